// Round 13
// baseline (1026.087 us; speedup 1.0000x reference)
//
#include <hip/hip_runtime.h>
#include <cstdint>
#include <cstddef>

#define N_TOKENS 16384
#define HIDDEN 1024
#define FFN 4096
#define NEXP 8
#define BM 256                        /* GEMM tile M (rows) */
#define BN 128                        /* GEMM tile N (cols) */
#define BKS 32                        /* K slot */
#define NBUF 3                        /* slot rotation depth: 3*(16+8)KB = 72 KB -> 2 blocks/CU */
#define MAXR (N_TOKENS*2 + NEXP*BM)   /* 34816 padded assignment rows */
#define MAXTILES (MAXR/BM)            /* 136 */

typedef __bf16 bf16;
typedef __attribute__((ext_vector_type(8))) __bf16 bf16x8;
typedef __attribute__((ext_vector_type(4))) __bf16 bf16x4;
typedef __attribute__((ext_vector_type(4))) float f32x4;

__device__ __forceinline__ void gload16(const void* g, void* l) {
  __builtin_amdgcn_global_load_lds((const __attribute__((address_space(1))) void*)g,
                                   (__attribute__((address_space(3))) void*)l, 16, 0, 0);
}

// bijective XCD swizzle (m204): contiguous wg chunk per XCD
__device__ __forceinline__ int xcd_swz(int orig, int nwg) {
  int q = nwg >> 3, r = nwg & 7;
  int xcd = orig & 7, idx = orig >> 3;
  int base = (xcd < r) ? xcd * (q + 1) : r * (q + 1) + (xcd - r) * q;
  return base + idx;
}

// ---------------- fused prep: convx | transconv(w1) | transconv(w2) | logits ----

#define PREP_CONVX_END  16384
#define PREP_W1_END     24576
#define PREP_W2_END     32768
#define PREP_LOGITS_END 33280

__global__ __launch_bounds__(256) void prep_k(const float* __restrict__ x,
                                              const float* __restrict__ wrt,
                                              const float* __restrict__ w1,
                                              const float* __restrict__ w2,
                                              bf16* __restrict__ xb,
                                              bf16* __restrict__ w1bT,
                                              bf16* __restrict__ w2bT,
                                              double* __restrict__ logitsE) {
  __shared__ __attribute__((aligned(16))) char smem[(NEXP * (HIDDEN + 1)) * 4];
  int b = blockIdx.x;
  int tid = threadIdx.x;

  if (b < PREP_CONVX_END) {
    int i = b * 256 + tid;
    float4 v = reinterpret_cast<const float4*>(x)[i];
    bf16x4 o = { (bf16)v.x, (bf16)v.y, (bf16)v.z, (bf16)v.w };
    *reinterpret_cast<bf16x4*>(xb + (size_t)i * 4) = o;
  } else if (b < PREP_W2_END) {
    float (*tile)[65] = reinterpret_cast<float (*)[65]>(smem);
    const float* src; bf16* dst; int R, C, bx, by, z;
    if (b < PREP_W1_END) {
      int idx = b - PREP_CONVX_END;
      z = idx >> 10; int rem = idx & 1023;
      bx = (rem & 63) * 64; by = (rem >> 6) * 64;
      R = HIDDEN; C = FFN; src = w1; dst = w1bT;
    } else {
      int idx = b - PREP_W1_END;
      z = idx >> 10; int rem = idx & 1023;
      bx = (rem & 15) * 64; by = (rem >> 4) * 64;
      R = FFN; C = HIDDEN; src = w2; dst = w2bT;
    }
    const float* s = src + (size_t)z * R * C;
    bf16* d = dst + (size_t)z * R * C;
    int tc = (tid & 15) * 4;
    int tr = tid >> 4;
    #pragma unroll
    for (int p = 0; p < 4; ++p) {
      int r = p * 16 + tr;
      float4 v = *reinterpret_cast<const float4*>(s + (size_t)(by + r) * C + bx + tc);
      tile[r][tc] = v.x; tile[r][tc + 1] = v.y; tile[r][tc + 2] = v.z; tile[r][tc + 3] = v.w;
    }
    __syncthreads();
    int wr = (tid & 15) * 4;
    int wc = tid >> 4;
    #pragma unroll
    for (int p = 0; p < 4; ++p) {
      int c = p * 16 + wc;
      bf16x4 o = { (bf16)tile[wr][c], (bf16)tile[wr + 1][c],
                   (bf16)tile[wr + 2][c], (bf16)tile[wr + 3][c] };
      *reinterpret_cast<bf16x4*>(d + (size_t)(bx + c) * R + by + wr) = o;
    }
  } else {
    float (*wT)[HIDDEN + 1] = reinterpret_cast<float (*)[HIDDEN + 1]>(smem);
    int lb = b - PREP_W2_END;
    for (int i = tid; i < HIDDEN * NEXP; i += 256) {
      int k = i >> 3, e = i & 7;
      wT[e][k] = wrt[i];
    }
    __syncthreads();
    int t = lb * 32 + (tid >> 3);
    int e = tid & 7;
    int goff = ((tid >> 3) & 7) * 4;
    const float* xr = x + (size_t)t * HIDDEN;
    double acc = 0.0;
    #pragma unroll 4
    for (int k = 0; k < HIDDEN; k += 4) {
      int kk = (k + goff) & (HIDDEN - 1);
      float4 v = *reinterpret_cast<const float4*>(xr + kk);
      acc += (double)v.x * (double)wT[e][kk];
      acc += (double)v.y * (double)wT[e][kk + 1];
      acc += (double)v.z * (double)wT[e][kk + 2];
      acc += (double)v.w * (double)wT[e][kk + 3];
    }
    logitsE[(size_t)e * N_TOKENS + t] = acc;
  }
}

// ---------------- router: top-2 + weights + histogram ----------------

__global__ __launch_bounds__(256) void route_k(const double* __restrict__ logitsE,
                                               int* __restrict__ expIdx,
                                               float* __restrict__ expW,
                                               int* __restrict__ counts) {
  __shared__ int lcnt[NEXP];
  int tid = threadIdx.x;
  if (tid < NEXP) lcnt[tid] = 0;
  __syncthreads();
  int n = blockIdx.x * 256 + tid;
  double lg[NEXP];
  #pragma unroll
  for (int e = 0; e < NEXP; ++e) lg[e] = logitsE[(size_t)e * N_TOKENS + n];
  int e1 = 0;
  #pragma unroll
  for (int e = 1; e < NEXP; ++e) if (lg[e] > lg[e1]) e1 = e;
  int e2 = (e1 == 0) ? 1 : 0;
  #pragma unroll
  for (int e = 0; e < NEXP; ++e)
    if (e != e1 && e != e2 && lg[e] > lg[e2]) e2 = e;
  double d = lg[e2] - lg[e1];                                      // <= 0
  float w1v = (float)(1.0 / (1.0 + exp(d)));
  expIdx[2 * n]     = e1; expIdx[2 * n + 1] = e2;
  expW[2 * n]       = w1v; expW[2 * n + 1]  = 1.0f - w1v;
  atomicAdd(&lcnt[e1], 1);
  atomicAdd(&lcnt[e2], 1);
  __syncthreads();
  if (tid < NEXP) atomicAdd(&counts[tid], lcnt[tid]);
}

// ---------------- segment offsets + scatter (256-aligned segments) ----------------

__global__ void offsets_k(const int* __restrict__ counts,
                          int* __restrict__ padOff, int* __restrict__ cursor) {
  if (threadIdx.x == 0) {
    int o = 0;
    for (int e = 0; e < NEXP; ++e) {
      padOff[e] = o;
      o += ((counts[e] + BM - 1) / BM) * BM;           // 256-aligned segments
    }
    padOff[NEXP] = o;
  }
  if (threadIdx.x < NEXP) cursor[threadIdx.x] = 0;
}

__global__ __launch_bounds__(256) void scatter_k(const int* __restrict__ expIdx,
                                                 const float* __restrict__ expW,
                                                 const int* __restrict__ padOff,
                                                 int* __restrict__ cursor,
                                                 int* __restrict__ rowTok,
                                                 float* __restrict__ rowW,
                                                 int* __restrict__ tokRow) {
  __shared__ int lcnt[NEXP], lbase[NEXP];
  int tid = threadIdx.x;
  if (tid < NEXP) lcnt[tid] = 0;
  __syncthreads();
  int n = blockIdx.x * 256 + tid;
  int e0 = expIdx[2 * n], e1 = expIdx[2 * n + 1];
  float w0 = expW[2 * n], w1 = expW[2 * n + 1];
  int p0 = atomicAdd(&lcnt[e0], 1);
  int p1 = atomicAdd(&lcnt[e1], 1);
  __syncthreads();
  if (tid < NEXP) lbase[tid] = atomicAdd(&cursor[tid], lcnt[tid]);
  __syncthreads();
  int r0 = padOff[e0] + lbase[e0] + p0;
  int r1 = padOff[e1] + lbase[e1] + p1;
  rowTok[r0] = n;  rowW[r0] = w0;  tokRow[2 * n]     = r0;
  rowTok[r1] = n;  rowW[r1] = w1;  tokRow[2 * n + 1] = r1;
}

// ---------------- 256x128 grouped GEMM core: 128x64 WAVE tiles ----------------
// LDS-BW analysis (R12 post-mortem): 64x64 wave tile = 512 B LDS-read/MFMA ->
// demand 422 B/cyc/CU at full MFMA rate > ~200-256 achievable -> the measured
// 25-31% MfmaUtil plateau. 128x64 wave tile: 12 frags (12 KB) feed 32 MFMA =
// 384 B/MFMA -> demand 316 B/cyc (-25%). Same R10 slot pipeline: depth-3,
// one barrier/step, counted vmcnt(6) (stage = 4A+2B = 6 loads/thread).
// 4 waves (2Mx2N), acc[8][4] (~200 VGPR, 2 waves/SIMD), 72 KB -> 2 blocks/CU.
// Swizzle (64-B rows, 0-conflict proven): phys octet = logical ^ ((row>>1)&3).

__device__ __forceinline__ float gelu_fast(float v) {
  float c = 1.5957691216057308f * (v + 0.044715f * v * v * v);   // 2*sqrt(2/pi)*(...)
  return v / (1.f + __expf(-c));
}

#define GEMM_CORE_LOOP(NT)                                                     \
  stage(0, 0); stage(1, 1);                                                    \
  int buf = 0, sbuf = 2;                                                       \
  _Pragma("unroll 1")                                                          \
  for (int s = 0; s < (NT); ++s) {                                             \
    if (s < (NT) - 1) asm volatile("s_waitcnt vmcnt(6)" ::: "memory");         \
    else              asm volatile("s_waitcnt vmcnt(0)" ::: "memory");         \
    __builtin_amdgcn_sched_barrier(0);                                         \
    __builtin_amdgcn_s_barrier();                                              \
    __builtin_amdgcn_sched_barrier(0);                                         \
    if (s + 2 < (NT)) stage(s + 2, sbuf);                                      \
    bf16x8 af[8], bfr[4];                                                      \
    _Pragma("unroll")                                                          \
    for (int m = 0; m < 8; ++m) af[m] = *reinterpret_cast<const bf16x8*>(&Ab[buf][aOff[m]]); \
    _Pragma("unroll")                                                          \
    for (int n = 0; n < 4; ++n) bfr[n] = *reinterpret_cast<const bf16x8*>(&Bb[buf][bOff[n]]); \
    __builtin_amdgcn_s_setprio(1);                                             \
    _Pragma("unroll")                                                          \
    for (int m = 0; m < 8; ++m)                                                \
      _Pragma("unroll")                                                        \
      for (int n = 0; n < 4; ++n)                                              \
        acc[m][n] = __builtin_amdgcn_mfma_f32_16x16x32_bf16(af[m], bfr[n], acc[m][n], 0, 0, 0); \
    __builtin_amdgcn_s_setprio(0);                                             \
    buf = (buf == NBUF - 1) ? 0 : buf + 1;                                     \
    sbuf = (sbuf == NBUF - 1) ? 0 : sbuf + 1;                                  \
  }

__global__ __launch_bounds__(256, 2) void gemm1_k(const bf16* __restrict__ xb,
                                                  const bf16* __restrict__ w1bT,
                                                  bf16* __restrict__ h,
                                                  const int* __restrict__ rowTok,
                                                  const int* __restrict__ padOff,
                                                  int tileStart, int rowStart,
                                                  int nBT) {
  __shared__ __attribute__((aligned(16))) bf16 Ab[NBUF][BM * BKS];   // 3x16 KB
  __shared__ __attribute__((aligned(16))) bf16 Bb[NBUF][BN * BKS];   // 3x8 KB
  // ct-group-of-8-major (proven R11: B group L2-resident, FETCH 650->245 MB)
  int wg = xcd_swz((int)blockIdx.x, (int)gridDim.x);
  int ctg = wg / (nBT * 8);
  int rem = wg % (nBT * 8);
  int bt = tileStart + rem / 8;
  int ct = ctg * 8 + (rem & 7);                     // nCT = FFN/BN = 32
  int r0 = bt * BM;
  if (r0 >= padOff[NEXP]) return;
  int e = 0;
  while (padOff[e + 1] <= r0) ++e;
  const bf16* Bbase = w1bT + ((size_t)e * FFN + (size_t)ct * BN) * HIDDEN;

  int tid = threadIdx.x;
  int lane = tid & 63, wave = tid >> 6;
  const bf16* aPtr[4]; const bf16* bPtr[2]; int aLds[4], bLds[2];
  #pragma unroll
  for (int j = 0; j < 4; ++j) {
    int ci = j * 256 + tid;
    int r = ci >> 2, sg = ci & 3;
    int ks = sg ^ ((r >> 1) & 3);
    int tok = rowTok[r0 + r]; if (tok < 0) tok = 0;
    aPtr[j] = xb + (size_t)tok * HIDDEN + ks * 8;
    aLds[j] = ci * 8;
  }
  #pragma unroll
  for (int j = 0; j < 2; ++j) {
    int ci = j * 256 + tid;
    int r = ci >> 2, sg = ci & 3;
    int ks = sg ^ ((r >> 1) & 3);
    bPtr[j] = Bbase + (size_t)r * HIDDEN + ks * 8;
    bLds[j] = ci * 8;
  }
  int lr = lane & 15, g = lane >> 4;
  int wm = wave >> 1, wn = wave & 1;
  int aOff[8], bOff[4];
  #pragma unroll
  for (int m = 0; m < 8; ++m) { int r = wm * 128 + m * 16 + lr; aOff[m] = r * BKS + ((g ^ ((r >> 1) & 3)) << 3); }
  #pragma unroll
  for (int n = 0; n < 4; ++n) { int r = wn * 64 + n * 16 + lr; bOff[n] = r * BKS + ((g ^ ((r >> 1) & 3)) << 3); }

  f32x4 acc[8][4];
  #pragma unroll
  for (int m = 0; m < 8; ++m)
    #pragma unroll
    for (int n = 0; n < 4; ++n) acc[m][n] = (f32x4){0.f, 0.f, 0.f, 0.f};

  const int NT = HIDDEN / BKS;                     // 32
  auto stage = [&](int sl, int b) {
    #pragma unroll
    for (int j = 0; j < 4; ++j) gload16(aPtr[j] + (size_t)sl * BKS, &Ab[b][aLds[j]]);
    #pragma unroll
    for (int j = 0; j < 2; ++j) gload16(bPtr[j] + (size_t)sl * BKS, &Bb[b][bLds[j]]);
  };
  GEMM_CORE_LOOP(NT)

  int colBase = ct * BN + wn * 64 + lr;
  #pragma unroll
  for (int m = 0; m < 8; ++m) {
    #pragma unroll
    for (int i = 0; i < 4; ++i) {
      int t = r0 + wm * 128 + m * 16 + g * 4 + i;
      bf16* hp = h + (size_t)(t - rowStart) * FFN + colBase;
      #pragma unroll
      for (int n = 0; n < 4; ++n)
        hp[n * 16] = (bf16)gelu_fast(acc[m][n][i]);
    }
  }
}

__global__ __launch_bounds__(256, 2) void gemm2_k(const bf16* __restrict__ h,
                                                  const bf16* __restrict__ w2bT,
                                                  bf16* __restrict__ y,
                                                  const int* __restrict__ padOff,
                                                  int tileStart, int rowStart) {
  __shared__ __attribute__((aligned(16))) bf16 Ab[NBUF][BM * BKS];
  __shared__ __attribute__((aligned(16))) bf16 Bb[NBUF][BN * BKS];
  const int nCT = HIDDEN / BN;                     // 8 col tiles
  int wg = xcd_swz((int)blockIdx.x, (int)gridDim.x);
  int bt = tileStart + wg / nCT;                   // bt-major: h-panel reuse
  int ct = wg % nCT;
  int r0 = bt * BM;
  if (r0 >= padOff[NEXP]) return;
  int e = 0;
  while (padOff[e + 1] <= r0) ++e;
  const bf16* Bbase = w2bT + ((size_t)e * HIDDEN + (size_t)ct * BN) * FFN;
  const bf16* Arow = h + (size_t)(r0 - rowStart) * FFN;

  int tid = threadIdx.x;
  int lane = tid & 63, wave = tid >> 6;
  const bf16* aPtr[4]; const bf16* bPtr[2]; int aLds[4], bLds[2];
  #pragma unroll
  for (int j = 0; j < 4; ++j) {
    int ci = j * 256 + tid;
    int r = ci >> 2, sg = ci & 3;
    int ks = sg ^ ((r >> 1) & 3);
    aPtr[j] = Arow + (size_t)r * FFN + ks * 8;
    aLds[j] = ci * 8;
  }
  #pragma unroll
  for (int j = 0; j < 2; ++j) {
    int ci = j * 256 + tid;
    int r = ci >> 2, sg = ci & 3;
    int ks = sg ^ ((r >> 1) & 3);
    bPtr[j] = Bbase + (size_t)r * FFN + ks * 8;
    bLds[j] = ci * 8;
  }
  int lr = lane & 15, g = lane >> 4;
  int wm = wave >> 1, wn = wave & 1;
  int aOff[8], bOff[4];
  #pragma unroll
  for (int m = 0; m < 8; ++m) { int r = wm * 128 + m * 16 + lr; aOff[m] = r * BKS + ((g ^ ((r >> 1) & 3)) << 3); }
  #pragma unroll
  for (int n = 0; n < 4; ++n) { int r = wn * 64 + n * 16 + lr; bOff[n] = r * BKS + ((g ^ ((r >> 1) & 3)) << 3); }

  f32x4 acc[8][4];
  #pragma unroll
  for (int m = 0; m < 8; ++m)
    #pragma unroll
    for (int n = 0; n < 4; ++n) acc[m][n] = (f32x4){0.f, 0.f, 0.f, 0.f};

  const int NT = FFN / BKS;                        // 128
  auto stage = [&](int sl, int b) {
    #pragma unroll
    for (int j = 0; j < 4; ++j) gload16(aPtr[j] + (size_t)sl * BKS, &Ab[b][aLds[j]]);
    #pragma unroll
    for (int j = 0; j < 2; ++j) gload16(bPtr[j] + (size_t)sl * BKS, &Bb[b][bLds[j]]);
  };
  GEMM_CORE_LOOP(NT)

  int colBase = ct * BN + wn * 64 + lr;
  #pragma unroll
  for (int m = 0; m < 8; ++m) {
    #pragma unroll
    for (int i = 0; i < 4; ++i) {
      int t = r0 + wm * 128 + m * 16 + g * 4 + i;
      bf16* yp = y + (size_t)t * HIDDEN + colBase;
      #pragma unroll
      for (int n = 0; n < 4; ++n)
        yp[n * 16] = (bf16)acc[m][n][i];
    }
  }
}

// ---------------- combine: out[n] = w0*y[r0] + w1*y[r1] (4 tokens/block) --------

__global__ __launch_bounds__(256) void combine_k(const bf16* __restrict__ y,
                                                 const int* __restrict__ tokRow,
                                                 const float* __restrict__ rowW,
                                                 float* __restrict__ out) {
  int wave = threadIdx.x >> 6, lane = threadIdx.x & 63;
  int n = blockIdx.x * 4 + wave;
  int c = lane * 16;
  int r0 = tokRow[2 * n], r1 = tokRow[2 * n + 1];
  float w0 = rowW[r0], w1 = rowW[r1];
  const bf16x8* pa = reinterpret_cast<const bf16x8*>(y + (size_t)r0 * HIDDEN + c);
  const bf16x8* pb = reinterpret_cast<const bf16x8*>(y + (size_t)r1 * HIDDEN + c);
  bf16x8 a0 = pa[0], a1 = pa[1];
  bf16x8 b0 = pb[0], b1 = pb[1];
  float* op = out + (size_t)n * HIDDEN + c;
  float4 o0, o1, o2, o3;
  #pragma unroll
  for (int j = 0; j < 4; ++j) {
    (&o0.x)[j] = w0 * (float)a0[j]     + w1 * (float)b0[j];
    (&o1.x)[j] = w0 * (float)a0[j + 4] + w1 * (float)b0[j + 4];
    (&o2.x)[j] = w0 * (float)a1[j]     + w1 * (float)b1[j];
    (&o3.x)[j] = w0 * (float)a1[j + 4] + w1 * (float)b1[j + 4];
  }
  reinterpret_cast<float4*>(op)[0] = o0;
  reinterpret_cast<float4*>(op)[1] = o1;
  reinterpret_cast<float4*>(op)[2] = o2;
  reinterpret_cast<float4*>(op)[3] = o3;
}

// ---------------- host ----------------

extern "C" void kernel_launch(void* const* d_in, const int* in_sizes, int n_in,
                              void* d_out, int out_size, void* d_ws, size_t ws_size,
                              hipStream_t stream) {
  const float* x   = (const float*)d_in[0];
  const float* wrt = (const float*)d_in[1];
  const float* w1  = (const float*)d_in[2];
  const float* w2  = (const float*)d_in[3];
  float* out = (float*)d_out;

  char* p = (char*)d_ws;
  size_t off = 0;
  auto alloc = [&](size_t bytes) -> void* {
    void* r = p + off;
    off = (off + bytes + 255) & ~(size_t)255;
    return r;
  };

  int*    counts  = (int*)   alloc(NEXP * 4);
  int*    padOff  = (int*)   alloc((NEXP + 1) * 4);
  int*    cursor  = (int*)   alloc(NEXP * 4);
  int*    expIdx  = (int*)   alloc((size_t)N_TOKENS * 2 * 4);
  float*  expW    = (float*) alloc((size_t)N_TOKENS * 2 * 4);
  int*    rowTok  = (int*)   alloc((size_t)MAXR * 4);
  float*  rowW    = (float*) alloc((size_t)MAXR * 4);
  int*    tokRow  = (int*)   alloc((size_t)N_TOKENS * 2 * 4);
  double* logitsE = (double*)alloc((size_t)NEXP * N_TOKENS * 8);
  bf16*   xb      = (bf16*)  alloc((size_t)N_TOKENS * HIDDEN * 2);
  bf16*   w1bT    = (bf16*)  alloc((size_t)NEXP * FFN * HIDDEN * 2);
  bf16*   w2bT    = (bf16*)  alloc((size_t)NEXP * FFN * HIDDEN * 2);
  bf16*   y       = (bf16*)  alloc((size_t)MAXR * HIDDEN * 2);
  size_t fixed = off;
  bf16* h = (bf16*)(p + fixed);

  size_t tileB = (size_t)BM * FFN * 2;             // 2 MiB per 256-row tile of h
  size_t avail = (ws_size > fixed) ? (ws_size - fixed) : tileB;
  size_t fitSz = avail / tileB;
  int tilesFit = (int)((fitSz < (size_t)MAXTILES) ? fitSz : (size_t)MAXTILES);
  if (tilesFit < 1) tilesFit = 1;
  int nchunks = (MAXTILES + tilesFit - 1) / tilesFit;
  int tpc = (MAXTILES + nchunks - 1) / nchunks;

  hipMemsetAsync(counts, 0, NEXP * 4, stream);
  hipMemsetAsync(rowTok, 0xFF, (size_t)MAXR * 4, stream);

  prep_k<<<PREP_LOGITS_END, 256, 0, stream>>>(x, wrt, w1, w2, xb, w1bT, w2bT, logitsE);
  route_k<<<N_TOKENS / 256, 256, 0, stream>>>(logitsE, expIdx, expW, counts);
  offsets_k<<<1, 64, 0, stream>>>(counts, padOff, cursor);
  scatter_k<<<N_TOKENS / 256, 256, 0, stream>>>(expIdx, expW, padOff, cursor, rowTok, rowW, tokRow);

  for (int c = 0; c < nchunks; ++c) {
    int ts = c * tpc;
    int rs = ts * BM;
    gemm1_k<<<tpc * (FFN / BN), 256, 0, stream>>>(xb, w1bT, h, rowTok, padOff, ts, rs, tpc);
    gemm2_k<<<tpc * (HIDDEN / BN), 256, 0, stream>>>(h, w2bT, y, padOff, ts, rs);
  }
  combine_k<<<N_TOKENS / 4, 256, 0, stream>>>(y, tokRow, rowW, out);
}

// Round 15
// 899.537 us; speedup vs baseline: 1.1407x; 1.1407x over previous
//
#include <hip/hip_runtime.h>
#include <cstdint>
#include <cstddef>

#define N_TOKENS 16384
#define HIDDEN 1024
#define FFN 4096
#define NEXP 8
#define BM 128                        /* GEMM tile (M and N) */
#define BKS 32                        /* K slot */
#define NBUF 3                        /* LDS slot rotation depth (48 KB -> 3 blocks/CU) */
#define MAXR (N_TOKENS*2 + NEXP*BM)   /* 33792 padded assignment rows */
#define MAXTILES (MAXR/BM)            /* 264 */

typedef __bf16 bf16;
typedef __attribute__((ext_vector_type(8))) __bf16 bf16x8;
typedef __attribute__((ext_vector_type(4))) __bf16 bf16x4;
typedef __attribute__((ext_vector_type(4))) float f32x4;

__device__ __forceinline__ void gload16(const void* g, void* l) {
  __builtin_amdgcn_global_load_lds((const __attribute__((address_space(1))) void*)g,
                                   (__attribute__((address_space(3))) void*)l, 16, 0, 0);
}

// bijective XCD swizzle (m204): contiguous wg chunk per XCD
__device__ __forceinline__ int xcd_swz(int orig, int nwg) {
  int q = nwg >> 3, r = nwg & 7;
  int xcd = orig & 7, idx = orig >> 3;
  int base = (xcd < r) ? xcd * (q + 1) : r * (q + 1) + (xcd - r) * q;
  return base + idx;
}

// ---------------- fused prep: convx | transconv(w1) | transconv(w2) | logits ----
// w1/w2 f32 streams are read-once -> nontemporal loads (don't evict x/xb from
// L3; x is re-read by the logits branch, xb/w1bT/w2bT by the GEMMs).

#define PREP_CONVX_END  16384
#define PREP_W1_END     24576
#define PREP_W2_END     32768
#define PREP_LOGITS_END 33280

__global__ __launch_bounds__(256) void prep_k(const float* __restrict__ x,
                                              const float* __restrict__ wrt,
                                              const float* __restrict__ w1,
                                              const float* __restrict__ w2,
                                              bf16* __restrict__ xb,
                                              bf16* __restrict__ w1bT,
                                              bf16* __restrict__ w2bT,
                                              double* __restrict__ logitsE) {
  __shared__ __attribute__((aligned(16))) char smem[(NEXP * (HIDDEN + 1)) * 4];
  int b = blockIdx.x;
  int tid = threadIdx.x;

  if (b < PREP_CONVX_END) {
    int i = b * 256 + tid;
    f32x4 v = reinterpret_cast<const f32x4*>(x)[i];
    bf16x4 o = { (bf16)v.x, (bf16)v.y, (bf16)v.z, (bf16)v.w };
    *reinterpret_cast<bf16x4*>(xb + (size_t)i * 4) = o;
  } else if (b < PREP_W2_END) {
    float (*tile)[65] = reinterpret_cast<float (*)[65]>(smem);
    const float* src; bf16* dst; int R, C, bx, by, z;
    if (b < PREP_W1_END) {
      int idx = b - PREP_CONVX_END;
      z = idx >> 10; int rem = idx & 1023;
      bx = (rem & 63) * 64; by = (rem >> 6) * 64;
      R = HIDDEN; C = FFN; src = w1; dst = w1bT;
    } else {
      int idx = b - PREP_W1_END;
      z = idx >> 10; int rem = idx & 1023;
      bx = (rem & 15) * 64; by = (rem >> 4) * 64;
      R = FFN; C = HIDDEN; src = w2; dst = w2bT;
    }
    const float* s = src + (size_t)z * R * C;
    bf16* d = dst + (size_t)z * R * C;
    int tc = (tid & 15) * 4;
    int tr = tid >> 4;
    #pragma unroll
    for (int p = 0; p < 4; ++p) {
      int r = p * 16 + tr;
      f32x4 v = __builtin_nontemporal_load(
          reinterpret_cast<const f32x4*>(s + (size_t)(by + r) * C + bx + tc));
      tile[r][tc] = v.x; tile[r][tc + 1] = v.y; tile[r][tc + 2] = v.z; tile[r][tc + 3] = v.w;
    }
    __syncthreads();
    int wr = (tid & 15) * 4;
    int wc = tid >> 4;
    #pragma unroll
    for (int p = 0; p < 4; ++p) {
      int c = p * 16 + wc;
      bf16x4 o = { (bf16)tile[wr][c], (bf16)tile[wr + 1][c],
                   (bf16)tile[wr + 2][c], (bf16)tile[wr + 3][c] };
      *reinterpret_cast<bf16x4*>(d + (size_t)(bx + c) * R + by + wr) = o;
    }
  } else {
    float (*wT)[HIDDEN + 1] = reinterpret_cast<float (*)[HIDDEN + 1]>(smem);
    int lb = b - PREP_W2_END;
    for (int i = tid; i < HIDDEN * NEXP; i += 256) {
      int k = i >> 3, e = i & 7;
      wT[e][k] = wrt[i];
    }
    __syncthreads();
    int t = lb * 32 + (tid >> 3);
    int e = tid & 7;
    int goff = ((tid >> 3) & 7) * 4;
    const float* xr = x + (size_t)t * HIDDEN;
    double acc = 0.0;
    #pragma unroll 4
    for (int k = 0; k < HIDDEN; k += 4) {
      int kk = (k + goff) & (HIDDEN - 1);
      f32x4 v = *reinterpret_cast<const f32x4*>(xr + kk);
      acc += (double)v.x * (double)wT[e][kk];
      acc += (double)v.y * (double)wT[e][kk + 1];
      acc += (double)v.z * (double)wT[e][kk + 2];
      acc += (double)v.w * (double)wT[e][kk + 3];
    }
    logitsE[(size_t)e * N_TOKENS + t] = acc;
  }
}

// ---------------- router: top-2 + weights + histogram ----------------

__global__ __launch_bounds__(256) void route_k(const double* __restrict__ logitsE,
                                               int* __restrict__ expIdx,
                                               float* __restrict__ expW,
                                               int* __restrict__ counts) {
  __shared__ int lcnt[NEXP];
  int tid = threadIdx.x;
  if (tid < NEXP) lcnt[tid] = 0;
  __syncthreads();
  int n = blockIdx.x * 256 + tid;
  double lg[NEXP];
  #pragma unroll
  for (int e = 0; e < NEXP; ++e) lg[e] = logitsE[(size_t)e * N_TOKENS + n];
  int e1 = 0;
  #pragma unroll
  for (int e = 1; e < NEXP; ++e) if (lg[e] > lg[e1]) e1 = e;
  int e2 = (e1 == 0) ? 1 : 0;
  #pragma unroll
  for (int e = 0; e < NEXP; ++e)
    if (e != e1 && e != e2 && lg[e] > lg[e2]) e2 = e;
  double d = lg[e2] - lg[e1];                                      // <= 0
  float w1v = (float)(1.0 / (1.0 + exp(d)));
  expIdx[2 * n]     = e1; expIdx[2 * n + 1] = e2;
  expW[2 * n]       = w1v; expW[2 * n + 1]  = 1.0f - w1v;
  atomicAdd(&lcnt[e1], 1);
  atomicAdd(&lcnt[e2], 1);
  __syncthreads();
  if (tid < NEXP) atomicAdd(&counts[tid], lcnt[tid]);
}

// ---------------- segment offsets + scatter ----------------

__global__ void offsets_k(const int* __restrict__ counts,
                          int* __restrict__ padOff, int* __restrict__ cursor) {
  if (threadIdx.x == 0) {
    int o = 0;
    for (int e = 0; e < NEXP; ++e) {
      padOff[e] = o;
      o += ((counts[e] + BM - 1) / BM) * BM;           // 128-aligned segments
    }
    padOff[NEXP] = o;
  }
  if (threadIdx.x < NEXP) cursor[threadIdx.x] = 0;
}

__global__ __launch_bounds__(256) void scatter_k(const int* __restrict__ expIdx,
                                                 const float* __restrict__ expW,
                                                 const int* __restrict__ padOff,
                                                 int* __restrict__ cursor,
                                                 int* __restrict__ rowTok,
                                                 float* __restrict__ rowW,
                                                 int* __restrict__ tokRow) {
  __shared__ int lcnt[NEXP], lbase[NEXP];
  int tid = threadIdx.x;
  if (tid < NEXP) lcnt[tid] = 0;
  __syncthreads();
  int n = blockIdx.x * 256 + tid;
  int e0 = expIdx[2 * n], e1 = expIdx[2 * n + 1];
  float w0 = expW[2 * n], w1 = expW[2 * n + 1];
  int p0 = atomicAdd(&lcnt[e0], 1);
  int p1 = atomicAdd(&lcnt[e1], 1);
  __syncthreads();
  if (tid < NEXP) lbase[tid] = atomicAdd(&cursor[tid], lcnt[tid]);
  __syncthreads();
  int r0 = padOff[e0] + lbase[e0] + p0;
  int r1 = padOff[e1] + lbase[e1] + p1;
  rowTok[r0] = n;  rowW[r0] = w0;  tokRow[2 * n]     = r0;
  rowTok[r1] = n;  rowW[r1] = w1;  tokRow[2 * n + 1] = r1;
}

// ---------------- 128^2 grouped GEMM core (R12 pipeline — proven best) ----------
// depth-3 rotation, 3 blocks/CU, one barrier/step, counted vmcnt(4).
// gemm1: ct-group-of-8-major (B group L2-resident, FETCH 650->245 MB).
// NEW (R15): h/y/out written with NONTEMPORAL stores — gemm1's 266 MB h write
// stream was evicting xb/w1bT from L3 (FETCH 245 vs 101 MB ideal), keeping
// staging at HBM latency (~900cy) beyond the 2-step lookahead.
// Swizzle (64-B rows, 0-conflict proven): phys octet = logical ^ ((row>>1)&3).

__device__ __forceinline__ float gelu_fast(float v) {
  float c = 1.5957691216057308f * (v + 0.044715f * v * v * v);   // 2*sqrt(2/pi)*(...)
  return v / (1.f + __expf(-c));
}

__global__ __launch_bounds__(256, 3) void gemm1_k(const bf16* __restrict__ xb,
                                                  const bf16* __restrict__ w1bT,
                                                  bf16* __restrict__ h,
                                                  const int* __restrict__ rowTok,
                                                  const int* __restrict__ padOff,
                                                  int tileStart, int rowStart,
                                                  int nBT) {
  __shared__ __attribute__((aligned(16))) bf16 Ab[NBUF][BM * BKS];
  __shared__ __attribute__((aligned(16))) bf16 Bb[NBUF][BM * BKS];
  int wg = xcd_swz((int)blockIdx.x, (int)gridDim.x);
  int ctg = wg / (nBT * 8);
  int rem = wg % (nBT * 8);
  int bt = tileStart + rem / 8;
  int ct = ctg * 8 + (rem & 7);
  int r0 = bt * BM;
  if (r0 >= padOff[NEXP]) return;
  int e = 0;
  while (padOff[e + 1] <= r0) ++e;
  const bf16* Bbase = w1bT + ((size_t)e * FFN + (size_t)ct * 128) * HIDDEN;

  int tid = threadIdx.x;
  int lane = tid & 63, wave = tid >> 6;
  const bf16* aPtr[2]; const bf16* bPtr[2]; int ldsOff[2];
  #pragma unroll
  for (int j = 0; j < 2; ++j) {
    int ci = j * 256 + tid;
    int r = ci >> 2, sg = ci & 3;
    int ks = sg ^ ((r >> 1) & 3);
    int tok = rowTok[r0 + r]; if (tok < 0) tok = 0;
    aPtr[j] = xb + (size_t)tok * HIDDEN + ks * 8;
    bPtr[j] = Bbase + (size_t)r * HIDDEN + ks * 8;
    ldsOff[j] = ci * 8;
  }
  int lr = lane & 15, g = lane >> 4;
  int wm = wave >> 1, wn = wave & 1;
  int aOff[4], bOff[4];
  #pragma unroll
  for (int m = 0; m < 4; ++m) { int r = wm * 64 + m * 16 + lr; aOff[m] = r * BKS + ((g ^ ((r >> 1) & 3)) << 3); }
  #pragma unroll
  for (int n = 0; n < 4; ++n) { int r = wn * 64 + n * 16 + lr; bOff[n] = r * BKS + ((g ^ ((r >> 1) & 3)) << 3); }

  f32x4 acc[4][4];
  #pragma unroll
  for (int m = 0; m < 4; ++m)
    #pragma unroll
    for (int n = 0; n < 4; ++n) acc[m][n] = (f32x4){0.f, 0.f, 0.f, 0.f};

  const int NT = HIDDEN / BKS;                     // 32
  auto stage = [&](int sl, int b) {
    #pragma unroll
    for (int j = 0; j < 2; ++j) gload16(aPtr[j] + (size_t)sl * BKS, &Ab[b][ldsOff[j]]);
    #pragma unroll
    for (int j = 0; j < 2; ++j) gload16(bPtr[j] + (size_t)sl * BKS, &Bb[b][ldsOff[j]]);
  };
  stage(0, 0); stage(1, 1);
  int buf = 0, sbuf = 2;
  #pragma unroll 1
  for (int s = 0; s < NT; ++s) {
    if (s < NT - 1) asm volatile("s_waitcnt vmcnt(4)" ::: "memory");
    else            asm volatile("s_waitcnt vmcnt(0)" ::: "memory");
    __builtin_amdgcn_sched_barrier(0);
    __builtin_amdgcn_s_barrier();
    __builtin_amdgcn_sched_barrier(0);
    if (s + 2 < NT) stage(s + 2, sbuf);
    bf16x8 af[4], bfr[4];
    #pragma unroll
    for (int m = 0; m < 4; ++m) af[m] = *reinterpret_cast<const bf16x8*>(&Ab[buf][aOff[m]]);
    #pragma unroll
    for (int n = 0; n < 4; ++n) bfr[n] = *reinterpret_cast<const bf16x8*>(&Bb[buf][bOff[n]]);
    __builtin_amdgcn_s_setprio(1);
    #pragma unroll
    for (int m = 0; m < 4; ++m)
      #pragma unroll
      for (int n = 0; n < 4; ++n)
        acc[m][n] = __builtin_amdgcn_mfma_f32_16x16x32_bf16(af[m], bfr[n], acc[m][n], 0, 0, 0);
    __builtin_amdgcn_s_setprio(0);
    buf = (buf == NBUF - 1) ? 0 : buf + 1;
    sbuf = (sbuf == NBUF - 1) ? 0 : sbuf + 1;
  }

  int colBase = ct * 128 + wn * 64 + lr;
  #pragma unroll
  for (int m = 0; m < 4; ++m) {
    #pragma unroll
    for (int i = 0; i < 4; ++i) {
      int t = r0 + wm * 64 + m * 16 + g * 4 + i;
      bf16* hp = h + (size_t)(t - rowStart) * FFN + colBase;
      #pragma unroll
      for (int n = 0; n < 4; ++n)
        __builtin_nontemporal_store((bf16)gelu_fast(acc[m][n][i]), hp + n * 16);
    }
  }
}

__global__ __launch_bounds__(256, 3) void gemm2_k(const bf16* __restrict__ h,
                                                  const bf16* __restrict__ w2bT,
                                                  bf16* __restrict__ y,
                                                  const int* __restrict__ padOff,
                                                  int tileStart, int rowStart) {
  __shared__ __attribute__((aligned(16))) bf16 Ab[NBUF][BM * BKS];
  __shared__ __attribute__((aligned(16))) bf16 Bb[NBUF][BM * BKS];
  const int nCT = HIDDEN / 128;                    // 8 col tiles
  int wg = xcd_swz((int)blockIdx.x, (int)gridDim.x);
  int bt = tileStart + wg / nCT;                   // bt-major: h-panel reuse
  int ct = wg % nCT;
  int r0 = bt * BM;
  if (r0 >= padOff[NEXP]) return;
  int e = 0;
  while (padOff[e + 1] <= r0) ++e;
  const bf16* Bbase = w2bT + ((size_t)e * HIDDEN + (size_t)ct * 128) * FFN;
  const bf16* Arow = h + (size_t)(r0 - rowStart) * FFN;

  int tid = threadIdx.x;
  int lane = tid & 63, wave = tid >> 6;
  const bf16* aPtr[2]; const bf16* bPtr[2]; int ldsOff[2];
  #pragma unroll
  for (int j = 0; j < 2; ++j) {
    int ci = j * 256 + tid;
    int r = ci >> 2, sg = ci & 3;
    int ks = sg ^ ((r >> 1) & 3);
    aPtr[j] = Arow + (size_t)r * FFN + ks * 8;
    bPtr[j] = Bbase + (size_t)r * FFN + ks * 8;
    ldsOff[j] = ci * 8;
  }
  int lr = lane & 15, g = lane >> 4;
  int wm = wave >> 1, wn = wave & 1;
  int aOff[4], bOff[4];
  #pragma unroll
  for (int m = 0; m < 4; ++m) { int r = wm * 64 + m * 16 + lr; aOff[m] = r * BKS + ((g ^ ((r >> 1) & 3)) << 3); }
  #pragma unroll
  for (int n = 0; n < 4; ++n) { int r = wn * 64 + n * 16 + lr; bOff[n] = r * BKS + ((g ^ ((r >> 1) & 3)) << 3); }

  f32x4 acc[4][4];
  #pragma unroll
  for (int m = 0; m < 4; ++m)
    #pragma unroll
    for (int n = 0; n < 4; ++n) acc[m][n] = (f32x4){0.f, 0.f, 0.f, 0.f};

  const int NT = FFN / BKS;                        // 128
  auto stage = [&](int sl, int b) {
    #pragma unroll
    for (int j = 0; j < 2; ++j) gload16(aPtr[j] + (size_t)sl * BKS, &Ab[b][ldsOff[j]]);
    #pragma unroll
    for (int j = 0; j < 2; ++j) gload16(bPtr[j] + (size_t)sl * BKS, &Bb[b][ldsOff[j]]);
  };
  stage(0, 0); stage(1, 1);
  int buf = 0, sbuf = 2;
  #pragma unroll 1
  for (int s = 0; s < NT; ++s) {
    if (s < NT - 1) asm volatile("s_waitcnt vmcnt(4)" ::: "memory");
    else            asm volatile("s_waitcnt vmcnt(0)" ::: "memory");
    __builtin_amdgcn_sched_barrier(0);
    __builtin_amdgcn_s_barrier();
    __builtin_amdgcn_sched_barrier(0);
    if (s + 2 < NT) stage(s + 2, sbuf);
    bf16x8 af[4], bfr[4];
    #pragma unroll
    for (int m = 0; m < 4; ++m) af[m] = *reinterpret_cast<const bf16x8*>(&Ab[buf][aOff[m]]);
    #pragma unroll
    for (int n = 0; n < 4; ++n) bfr[n] = *reinterpret_cast<const bf16x8*>(&Bb[buf][bOff[n]]);
    __builtin_amdgcn_s_setprio(1);
    #pragma unroll
    for (int m = 0; m < 4; ++m)
      #pragma unroll
      for (int n = 0; n < 4; ++n)
        acc[m][n] = __builtin_amdgcn_mfma_f32_16x16x32_bf16(af[m], bfr[n], acc[m][n], 0, 0, 0);
    __builtin_amdgcn_s_setprio(0);
    buf = (buf == NBUF - 1) ? 0 : buf + 1;
    sbuf = (sbuf == NBUF - 1) ? 0 : sbuf + 1;
  }

  int colBase = ct * 128 + wn * 64 + lr;
  #pragma unroll
  for (int m = 0; m < 4; ++m) {
    #pragma unroll
    for (int i = 0; i < 4; ++i) {
      int t = r0 + wm * 64 + m * 16 + g * 4 + i;
      bf16* yp = y + (size_t)t * HIDDEN + colBase;
      #pragma unroll
      for (int n = 0; n < 4; ++n)
        __builtin_nontemporal_store((bf16)acc[m][n][i], yp + n * 16);
    }
  }
}

// ---------------- combine: out[n] = w0*y[r0] + w1*y[r1] (4 tokens/block) --------

__global__ __launch_bounds__(256) void combine_k(const bf16* __restrict__ y,
                                                 const int* __restrict__ tokRow,
                                                 const float* __restrict__ rowW,
                                                 float* __restrict__ out) {
  int wave = threadIdx.x >> 6, lane = threadIdx.x & 63;
  int n = blockIdx.x * 4 + wave;
  int c = lane * 16;
  int r0 = tokRow[2 * n], r1 = tokRow[2 * n + 1];
  float w0 = rowW[r0], w1 = rowW[r1];
  const bf16x8* pa = reinterpret_cast<const bf16x8*>(y + (size_t)r0 * HIDDEN + c);
  const bf16x8* pb = reinterpret_cast<const bf16x8*>(y + (size_t)r1 * HIDDEN + c);
  bf16x8 a0 = pa[0], a1 = pa[1];
  bf16x8 b0 = pb[0], b1 = pb[1];
  float* op = out + (size_t)n * HIDDEN + c;
  f32x4 o0, o1, o2, o3;
  #pragma unroll
  for (int j = 0; j < 4; ++j) {
    o0[j] = w0 * (float)a0[j]     + w1 * (float)b0[j];
    o1[j] = w0 * (float)a0[j + 4] + w1 * (float)b0[j + 4];
    o2[j] = w0 * (float)a1[j]     + w1 * (float)b1[j];
    o3[j] = w0 * (float)a1[j + 4] + w1 * (float)b1[j + 4];
  }
  __builtin_nontemporal_store(o0, reinterpret_cast<f32x4*>(op) + 0);
  __builtin_nontemporal_store(o1, reinterpret_cast<f32x4*>(op) + 1);
  __builtin_nontemporal_store(o2, reinterpret_cast<f32x4*>(op) + 2);
  __builtin_nontemporal_store(o3, reinterpret_cast<f32x4*>(op) + 3);
}

// ---------------- host ----------------

extern "C" void kernel_launch(void* const* d_in, const int* in_sizes, int n_in,
                              void* d_out, int out_size, void* d_ws, size_t ws_size,
                              hipStream_t stream) {
  const float* x   = (const float*)d_in[0];
  const float* wrt = (const float*)d_in[1];
  const float* w1  = (const float*)d_in[2];
  const float* w2  = (const float*)d_in[3];
  float* out = (float*)d_out;

  char* p = (char*)d_ws;
  size_t off = 0;
  auto alloc = [&](size_t bytes) -> void* {
    void* r = p + off;
    off = (off + bytes + 255) & ~(size_t)255;
    return r;
  };

  int*    counts  = (int*)   alloc(NEXP * 4);
  int*    padOff  = (int*)   alloc((NEXP + 1) * 4);
  int*    cursor  = (int*)   alloc(NEXP * 4);
  int*    expIdx  = (int*)   alloc((size_t)N_TOKENS * 2 * 4);
  float*  expW    = (float*) alloc((size_t)N_TOKENS * 2 * 4);
  int*    rowTok  = (int*)   alloc((size_t)MAXR * 4);
  float*  rowW    = (float*) alloc((size_t)MAXR * 4);
  int*    tokRow  = (int*)   alloc((size_t)N_TOKENS * 2 * 4);
  double* logitsE = (double*)alloc((size_t)NEXP * N_TOKENS * 8);
  bf16*   xb      = (bf16*)  alloc((size_t)N_TOKENS * HIDDEN * 2);
  bf16*   w1bT    = (bf16*)  alloc((size_t)NEXP * FFN * HIDDEN * 2);
  bf16*   w2bT    = (bf16*)  alloc((size_t)NEXP * FFN * HIDDEN * 2);
  bf16*   y       = (bf16*)  alloc((size_t)MAXR * HIDDEN * 2);
  size_t fixed = off;
  bf16* h = (bf16*)(p + fixed);

  size_t tileB = (size_t)BM * FFN * 2;             // 1 MiB per 128-row tile of h
  size_t avail = (ws_size > fixed) ? (ws_size - fixed) : tileB;
  size_t fitSz = avail / tileB;
  int tilesFit = (int)((fitSz < (size_t)MAXTILES) ? fitSz : (size_t)MAXTILES);
  if (tilesFit < 1) tilesFit = 1;
  int nchunks = (MAXTILES + tilesFit - 1) / tilesFit;
  int tpc = (MAXTILES + nchunks - 1) / nchunks;

  hipMemsetAsync(counts, 0, NEXP * 4, stream);
  hipMemsetAsync(rowTok, 0xFF, (size_t)MAXR * 4, stream);

  prep_k<<<PREP_LOGITS_END, 256, 0, stream>>>(x, wrt, w1, w2, xb, w1bT, w2bT, logitsE);
  route_k<<<N_TOKENS / 256, 256, 0, stream>>>(logitsE, expIdx, expW, counts);
  offsets_k<<<1, 64, 0, stream>>>(counts, padOff, cursor);
  scatter_k<<<N_TOKENS / 256, 256, 0, stream>>>(expIdx, expW, padOff, cursor, rowTok, rowW, tokRow);

  for (int c = 0; c < nchunks; ++c) {
    int ts = c * tpc;
    int rs = ts * BM;
    gemm1_k<<<tpc * (FFN / 128), 256, 0, stream>>>(xb, w1bT, h, rowTok, padOff, ts, rs, tpc);
    gemm2_k<<<tpc * (HIDDEN / 128), 256, 0, stream>>>(h, w2bT, y, padOff, ts, rs);
  }
  combine_k<<<N_TOKENS / 4, 256, 0, stream>>>(y, tokRow, rowW, out);
}